// Round 7
// baseline (223.934 us; speedup 1.0000x reference)
//
#include <hip/hip_runtime.h>
#include <hip/hip_bf16.h>
#include <math.h>

#define N_NODES 100000
#define N_EDGES 1600000
#define D_FEAT 32
#define D_HID 64
#define D_OUT 64
#define CAP 48          // per-node slot capacity; deg ~ Poisson(16), safe
#define NPB 64          // nodes per coarse bucket (1<<6)
#define NBKT 1563       // ceil(100000/64)
#define ECAP 1536       // edge capacity per coarse bucket (mean 1024, ~16 sigma)
#define B1 200          // binning blocks
#define E_PER_B1 8000   // 200 * 8000 = 1.6M edges exactly (div by 4)
#define NB_NODE 1024    // node-precompute blocks

typedef short bf16x8 __attribute__((ext_vector_type(8)));
typedef float f32x4  __attribute__((ext_vector_type(4)));

__device__ inline unsigned short f2bf(float f) {   // RNE f32 -> bf16
    unsigned u = __float_as_uint(f);
    u += 0x7fff + ((u >> 16) & 1);
    return (unsigned short)(u >> 16);
}
__device__ inline float bf2f(unsigned short h) {
    return __uint_as_float(((unsigned)h) << 16);
}
__device__ inline unsigned pack2bf(float lo, float hi) {   // -> [hi|lo] u32
    return ((unsigned)f2bf(hi) << 16) | (unsigned)f2bf(lo);
}

union afu { uint4 u; bf16x8 v; };

// Build one A-fragment (8 bf16) from a packed vb row chunk and f32 q chunk:
// af[2m]   = relu(bf2f(lo16(w_m)) - qk[2m])
// af[2m+1] = relu(bf2f(hi16(w_m)) - qk[2m+1])
__device__ inline afu abuild(uint4 vv, const float* qk) {
    afu af;
#pragma unroll
    for (int m = 0; m < 4; ++m) {
        unsigned w = (&vv.x)[m];
        float flo = __uint_as_float(w << 16);
        float fhi = __uint_as_float(w & 0xFFFF0000u);
        float hlo = fmaxf(flo - qk[2 * m],     0.0f);
        float hhi = fmaxf(fhi - qk[2 * m + 1], 0.0f);
        (&af.u.x)[m] = pack2bf(hlo, hhi);
    }
    return af;
}

// ---------------------------------------------------------------------------
// Kernel 1: per-node precompute (f32 math, bf16 store)
//   q[n][k] = pos[n] @ W1[32:35];  v[n][k] = b1[k] + x[n] @ W1[:32] + q[n][k]
// per-edge layer-1 output = relu(v[src] - q[dst]).
// ---------------------------------------------------------------------------
__global__ __launch_bounds__(256)
void node_kernel(const float* __restrict__ x,
                 const float* __restrict__ pos,
                 const float* __restrict__ W1,
                 const float* __restrict__ b1,
                 unsigned short* __restrict__ vb,
                 unsigned short* __restrict__ qb) {
    const int lane = threadIdx.x & 63;
    const int wid  = (blockIdx.x * blockDim.x + threadIdx.x) >> 6;
    const int nw   = (NB_NODE * 256) >> 6;

    float w[D_FEAT + 3];
#pragma unroll
    for (int f = 0; f < D_FEAT + 3; ++f)
        w[f] = W1[f * D_HID + lane];
    const float bb = b1[lane];

    for (int node = wid; node < N_NODES; node += nw) {
        const float* xr = x + (size_t)node * D_FEAT;
        float acc = bb;
#pragma unroll
        for (int f = 0; f < D_FEAT; ++f)
            acc = fmaf(xr[f], w[f], acc);

        const float* pr = pos + (size_t)node * 3;
        float qa = 0.0f;
#pragma unroll
        for (int p = 0; p < 3; ++p)
            qa = fmaf(pr[p], w[D_FEAT + p], qa);

        vb[(size_t)node * D_HID + lane] = f2bf(acc + qa);
        qb[(size_t)node * D_HID + lane] = f2bf(qa);
    }
}

// ---------------------------------------------------------------------------
// Kernel 2: two-phase binning into 1563 coarse buckets of 64 dst-nodes.
// int4 edge loads: 4 independent atomic->store chains per thread-iteration
// (ILP for latency hiding). Per block: LDS histogram -> one global atomicAdd
// per active bucket reserving a contiguous range -> placement via LDS
// cursors (dense appends, ~5 entries per block-bucket ~ 20B/64B line).
// Entry packing: (src << 6) | (dst & 63).
// ---------------------------------------------------------------------------
__global__ __launch_bounds__(1024)
void bin_kernel(const int* __restrict__ src,
                const int* __restrict__ dst,
                int* __restrict__ gcnt,
                unsigned int* __restrict__ coarse) {
    __shared__ int hist[NBKT];
    const int tid = threadIdx.x;
    const int e0 = blockIdx.x * E_PER_B1;
    const int nq = E_PER_B1 / 4;            // 2000 int4 per block

    for (int b = tid; b < NBKT; b += 1024) hist[b] = 0;
    __syncthreads();

    const int4* d4p = (const int4*)(dst + e0);
    const int4* s4p = (const int4*)(src + e0);

    for (int i = tid; i < nq; i += 1024) {
        int4 d4 = d4p[i];
        atomicAdd(&hist[d4.x >> 6], 1);
        atomicAdd(&hist[d4.y >> 6], 1);
        atomicAdd(&hist[d4.z >> 6], 1);
        atomicAdd(&hist[d4.w >> 6], 1);
    }
    __syncthreads();

    for (int b = tid; b < NBKT; b += 1024) {
        int c = hist[b];
        hist[b] = (c > 0) ? atomicAdd(&gcnt[b], c) : 0;
    }
    __syncthreads();

    for (int i = tid; i < nq; i += 1024) {
        int4 d4 = d4p[i];
        int4 s4 = s4p[i];
        int p0 = atomicAdd(&hist[d4.x >> 6], 1);
        int p1 = atomicAdd(&hist[d4.y >> 6], 1);
        int p2 = atomicAdd(&hist[d4.z >> 6], 1);
        int p3 = atomicAdd(&hist[d4.w >> 6], 1);
        if (p0 < ECAP) coarse[(size_t)(d4.x >> 6) * ECAP + p0] = ((unsigned)s4.x << 6) | (unsigned)(d4.x & 63);
        if (p1 < ECAP) coarse[(size_t)(d4.y >> 6) * ECAP + p1] = ((unsigned)s4.y << 6) | (unsigned)(d4.y & 63);
        if (p2 < ECAP) coarse[(size_t)(d4.z >> 6) * ECAP + p2] = ((unsigned)s4.z << 6) | (unsigned)(d4.z & 63);
        if (p3 < ECAP) coarse[(size_t)(d4.w >> 6) * ECAP + p3] = ((unsigned)s4.w << 6) | (unsigned)(d4.w & 63);
    }
}

// ---------------------------------------------------------------------------
// Kernel 3: fused fine-bucketing + per-node MFMA aggregation.
// Block = one coarse bucket, 256 threads = 4 waves. Per-node slot lists in
// LDS; each wave aggregates 16 nodes. Per node, TWO 16-row batches are
// processed concurrently (rows padded to 32 ~ avg real rows 18): two
// independent gather -> A-build -> MFMA chains per iteration for ILP, same
// MFMA count as the sequential version on average. Layer-2 via
// mfma_f32_16x16x32_bf16 (4 col-tiles x 2 K-halves x 2 row-batches),
// register max, one coalesced store. Padding rows use src=node (self-loop,
// idempotent under max).
// ---------------------------------------------------------------------------
__global__ __launch_bounds__(256)
void agg_kernel(const unsigned short* __restrict__ vb,
                const unsigned short* __restrict__ qb,
                const float* __restrict__ W2,
                const float* __restrict__ b2,
                const int* __restrict__ gcnt,
                const unsigned int* __restrict__ coarse,
                float* __restrict__ out) {
    __shared__ int lcnt[NPB];
    __shared__ int lslots[NPB][CAP];

    const int tid  = threadIdx.x;
    const int lane = tid & 63;
    const int wave = tid >> 6;             // 0..3
    const int quad = lane >> 4;
    const int mrow = lane & 15;
    const int bkt  = blockIdx.x;
    const int nbase = bkt << 6;

    // B fragments: bfrag[t][kh][j] = W2[kh*32 + quad*8 + j][t*16 + mrow]
    bf16x8 bfrag[4][2];
#pragma unroll
    for (int t = 0; t < 4; ++t)
#pragma unroll
        for (int kh = 0; kh < 2; ++kh) {
            bf16x8 f;
#pragma unroll
            for (int j = 0; j < 8; ++j)
                f[j] = (short)f2bf(W2[(kh * 32 + quad * 8 + j) * D_OUT + t * 16 + mrow]);
            bfrag[t][kh] = f;
        }
    float bias[4];
#pragma unroll
    for (int t = 0; t < 4; ++t) bias[t] = b2[t * 16 + mrow];

    // fine bucketing into LDS
    int E_b = gcnt[bkt];
    if (E_b > ECAP) E_b = ECAP;
    for (int i = tid; i < NPB; i += 256) lcnt[i] = 0;
    __syncthreads();
    for (int i = tid; i < E_b; i += 256) {
        unsigned enc = coarse[(size_t)bkt * ECAP + i];
        int local = (int)(enc & 63u);
        int s     = (int)(enc >> 6);
        int p = atomicAdd(&lcnt[local], 1);
        if (p < CAP) lslots[local][p] = s;
    }
    __syncthreads();

    // per-node aggregation, 16 nodes per wave, 2 batches in flight
    for (int ln = wave; ln < NPB; ln += 4) {
        const int node = nbase + ln;
        if (node >= N_NODES) break;

        // q chunk of node (f32) for both K-halves: qf[kh][j]
        float qf[2][8];
#pragma unroll
        for (int kh = 0; kh < 2; ++kh) {
            bf16x8 qv = *(const bf16x8*)(qb + (size_t)node * D_HID + kh * 32 + quad * 8);
#pragma unroll
            for (int j = 0; j < 8; ++j) qf[kh][j] = bf2f((unsigned short)qv[j]);
        }

        int deg = lcnt[ln];
        if (deg > CAP) deg = CAP;
        const int rows = deg + 1;              // + self-loop
        const int npair = (rows + 31) >> 5;    // 32-row pairs (1 for 96.6%)

        float rmax[4][4];
#pragma unroll
        for (int t = 0; t < 4; ++t)
#pragma unroll
            for (int r = 0; r < 4; ++r) rmax[t][r] = -INFINITY;

        const uint4* vbq = (const uint4*)vb;   // row = 8 uint4
        for (int p = 0; p < npair; ++p) {
            int ia = (p << 5) + mrow;
            int ib = ia + 16;
            int sA = (ia < deg) ? lslots[ln][ia] : node;
            int sB = (ib < deg) ? lslots[ln][ib] : node;

            const uint4* pa = vbq + (size_t)sA * 8 + quad;
            const uint4* pb = vbq + (size_t)sB * 8 + quad;
            uint4 vA0 = pa[0], vA1 = pa[4];    // kh=0 / kh=1 chunks
            uint4 vB0 = pb[0], vB1 = pb[4];

            afu aA0 = abuild(vA0, qf[0]);
            afu aA1 = abuild(vA1, qf[1]);
            afu aB0 = abuild(vB0, qf[0]);
            afu aB1 = abuild(vB1, qf[1]);

#pragma unroll
            for (int t = 0; t < 4; ++t) {
                f32x4 accA = (f32x4){0.f, 0.f, 0.f, 0.f};
                f32x4 accB = (f32x4){0.f, 0.f, 0.f, 0.f};
                accA = __builtin_amdgcn_mfma_f32_16x16x32_bf16(aA0.v, bfrag[t][0], accA, 0, 0, 0);
                accB = __builtin_amdgcn_mfma_f32_16x16x32_bf16(aB0.v, bfrag[t][0], accB, 0, 0, 0);
                accA = __builtin_amdgcn_mfma_f32_16x16x32_bf16(aA1.v, bfrag[t][1], accA, 0, 0, 0);
                accB = __builtin_amdgcn_mfma_f32_16x16x32_bf16(aB1.v, bfrag[t][1], accB, 0, 0, 0);
#pragma unroll
                for (int r = 0; r < 4; ++r)
                    rmax[t][r] = fmaxf(rmax[t][r], fmaxf(accA[r], accB[r]));
            }
        }

        float fin[4];
#pragma unroll
        for (int t = 0; t < 4; ++t) {
            float m = fmaxf(fmaxf(rmax[t][0], rmax[t][1]), fmaxf(rmax[t][2], rmax[t][3]));
            m = fmaxf(m, __shfl_xor(m, 16, 64));
            m = fmaxf(m, __shfl_xor(m, 32, 64));
            fin[t] = m + bias[t];
        }
        float r = (quad == 0) ? fin[0] : (quad == 1) ? fin[1] : (quad == 2) ? fin[2] : fin[3];
        out[(size_t)node * D_OUT + lane] = r;
    }
}

// ---------------------------------------------------------------------------
extern "C" void kernel_launch(void* const* d_in, const int* in_sizes, int n_in,
                              void* d_out, int out_size, void* d_ws, size_t ws_size,
                              hipStream_t stream) {
    const float* x   = (const float*)d_in[0];
    const float* pos = (const float*)d_in[1];
    const int*   ei  = (const int*)d_in[2];   // [2][N_EDGES]: row0=src, row1=dst
    const float* W1  = (const float*)d_in[3];
    const float* b1  = (const float*)d_in[4];
    const float* W2  = (const float*)d_in[5];
    const float* b2  = (const float*)d_in[6];
    float* out = (float*)d_out;

    char* ws = (char*)d_ws;
    unsigned short* vb   = (unsigned short*)ws;                     // 12.8 MB
    unsigned short* qb   = (unsigned short*)(ws + 12800000);        // 12.8 MB
    int*            gcnt = (int*)(ws + 25600000);                   // 6.3 KB
    unsigned int* coarse = (unsigned int*)(ws + 25610240);          // 9.6 MB

    const int* src = ei;
    const int* dst = ei + N_EDGES;

    (void)hipMemsetAsync(gcnt, 0, NBKT * sizeof(int), stream);
    hipLaunchKernelGGL(bin_kernel, dim3(B1), dim3(1024), 0, stream,
                       src, dst, gcnt, coarse);
    hipLaunchKernelGGL(node_kernel, dim3(NB_NODE), dim3(256), 0, stream,
                       x, pos, W1, b1, vb, qb);
    hipLaunchKernelGGL(agg_kernel, dim3(NBKT), dim3(256), 0, stream,
                       vb, qb, W2, b2, gcnt, coarse, out);
}